// Round 1
// 301.317 us; speedup vs baseline: 1.0342x; 1.0342x over previous
//
#include <hip/hip_runtime.h>
#include <hip/hip_fp16.h>

// GraphSAGE 3-layer. CSR via two-level counting sort. fp16 feature tables
// (N+1 rows; row N zeroed for branchless gather prefetch). agg stored fp16.
// Layer-2 GEMM fuses the layer-3 per-node dots (t,s); h2 never materialized.
// R1: both GEMMs moved from VALU fp32 (LDS-staged) to v_mfma_f32_16x16x16_f16,
//     no LDS, W converted fp32->fp16 in-register per wave (W is L1-resident).
//
// ws: offs | scol | xh h[(N+1)*64] | h1 h[(N+1)*64] | aggh h[N*64] | tarr f[N] | sarr f[N]
//     (sort scratch ebuf/hist/histsc/part aliases the aggh region)

#define CH 64
#define BKT_SHIFT 9
#define BKT_ROWS 512
#define NBLK 256   // pass A/B blocks; requires nbk <= 256 (N <= 131072)
#define SCAP 12288 // LDS staging capacity in k_build (avg bucket ~8192)

typedef _Float16 half4_t __attribute__((ext_vector_type(4)));
typedef float f32x4 __attribute__((ext_vector_type(4)));

// ---- Pass A: per-block bucket histogram, layout hist[bucket][NBLK] ----
__global__ __launch_bounds__(256) void k_hist(const int* __restrict__ row,
                                              int* __restrict__ hist,
                                              int E, int nbk, int per_blk) {
    __shared__ int h[256];
    int t = threadIdx.x;
    h[t] = 0;
    __syncthreads();
    int s = blockIdx.x * per_blk;
    int e = min(s + per_blk, E);
    for (int i = s + t; i < e; i += 256)
        atomicAdd(&h[row[i] >> BKT_SHIFT], 1);
    __syncthreads();
    if (t < nbk) hist[t * NBLK + blockIdx.x] = h[t];
}

// ---- parallel 3-kernel exclusive scan over M ints ----
__global__ __launch_bounds__(256) void k_ssum(const int* __restrict__ a,
                                              int* __restrict__ part, int M) {
    __shared__ int ts[256];
    int t = threadIdx.x;
    int g0 = blockIdx.x * 1024 + t * 4;
    int s = 0;
#pragma unroll
    for (int i = 0; i < 4; ++i)
        if (g0 + i < M) s += a[g0 + i];
    ts[t] = s;
    __syncthreads();
    for (int off = 128; off >= 1; off >>= 1) {
        if (t < off) ts[t] += ts[t + off];
        __syncthreads();
    }
    if (t == 0) part[blockIdx.x] = ts[0];
}

__global__ void k_sser(int* part, int nb) {
    if (threadIdx.x == 0) {
        int run = 0;
        for (int b = 0; b < nb; ++b) { int v = part[b]; part[b] = run; run += v; }
    }
}

__global__ __launch_bounds__(256) void k_sscan(const int* __restrict__ a,
                                               const int* __restrict__ part,
                                               int* __restrict__ o, int M) {
    __shared__ int ts[256];
    int t = threadIdx.x;
    int g0 = blockIdx.x * 1024 + t * 4;
    int d[4];
    int s = 0;
#pragma unroll
    for (int i = 0; i < 4; ++i) {
        d[i] = (g0 + i < M) ? a[g0 + i] : 0;
        s += d[i];
    }
    ts[t] = s;
    __syncthreads();
    for (int off = 1; off < 256; off <<= 1) {
        int v = (t >= off) ? ts[t - off] : 0;
        __syncthreads();
        ts[t] += v;
        __syncthreads();
    }
    int run = part[blockIdx.x] + ts[t] - s;
#pragma unroll
    for (int i = 0; i < 4; ++i) {
        if (g0 + i < M) o[g0 + i] = run;
        run += d[i];
    }
}

// ---- Pass B: place packed (rowlocal<<17 | col) into bucket-ordered ebuf ----
__global__ __launch_bounds__(256) void k_binscatter(const int* __restrict__ row,
                                                    const int* __restrict__ col,
                                                    const int* __restrict__ histsc,
                                                    int* __restrict__ ebuf,
                                                    int E, int nbk, int per_blk) {
    __shared__ int cur[256];
    int t = threadIdx.x;
    cur[t] = (t < nbk) ? histsc[t * NBLK + blockIdx.x] : 0;
    __syncthreads();
    int s = blockIdx.x * per_blk;
    int e = min(s + per_blk, E);
    for (int i = s + t; i < e; i += 256) {
        int r = row[i];
        int b = r >> BKT_SHIFT;
        int p = atomicAdd(&cur[b], 1);
        ebuf[p] = ((r & (BKT_ROWS - 1)) << 17) | col[i];
    }
}

// ---- Pass C: per-bucket CSR build; scol staged in LDS, coalesced out ----
__global__ __launch_bounds__(256) void k_build(const int* __restrict__ histsc,
                                               const int* __restrict__ ebuf,
                                               int* __restrict__ offs,
                                               int* __restrict__ scol,
                                               int N, int E, int nbk) {
    __shared__ int cnt[BKT_ROWS];
    __shared__ int loff[BKT_ROWS];
    __shared__ int ts[256];
    __shared__ int sbuf[SCAP];
    int b = blockIdx.x, t = threadIdx.x;
    int g0 = histsc[b * NBLK];
    int g1 = (b + 1 < nbk) ? histsc[(b + 1) * NBLK] : E;
    cnt[t] = 0;
    cnt[t + 256] = 0;
    __syncthreads();
    for (int i = g0 + t; i < g1; i += 256)
        atomicAdd(&cnt[((unsigned)ebuf[i]) >> 17], 1);
    __syncthreads();
    int c0 = cnt[2 * t], c1 = cnt[2 * t + 1];
    ts[t] = c0 + c1;
    __syncthreads();
    for (int off = 1; off < 256; off <<= 1) {
        int v = (t >= off) ? ts[t - off] : 0;
        __syncthreads();
        ts[t] += v;
        __syncthreads();
    }
    int ex = ts[t] - (c0 + c1);
    loff[2 * t] = ex;
    loff[2 * t + 1] = ex + c0;
    __syncthreads();
    int r0 = b << BKT_SHIFT;
    for (int r = t; r < BKT_ROWS; r += 256)
        if (r0 + r < N) offs[r0 + r] = g0 + loff[r];
    if (b == nbk - 1 && t == 0) offs[N] = E;
    cnt[t] = 0;
    cnt[t + 256] = 0;
    __syncthreads();
    int sz = g1 - g0;
    if (sz <= SCAP) {
        for (int i = g0 + t; i < g1; i += 256) {
            unsigned v = (unsigned)ebuf[i];
            int rl = v >> 17;
            int p = atomicAdd(&cnt[rl], 1);
            sbuf[loff[rl] + p] = (int)(v & 0x1FFFFu);
        }
        __syncthreads();
        for (int i = t; i < sz; i += 256) scol[g0 + i] = sbuf[i];
    } else {
        for (int i = g0 + t; i < g1; i += 256) {
            unsigned v = (unsigned)ebuf[i];
            int rl = v >> 17;
            int p = atomicAdd(&cnt[rl], 1);
            scol[g0 + loff[rl] + p] = (int)(v & 0x1FFFFu);
        }
    }
}

// ---- fp32 -> fp16 table; also zeroes dummy row N of xh and h1 ----
__global__ __launch_bounds__(256) void k_tohalf(const float* __restrict__ X,
                                                __half* __restrict__ XH,
                                                __half* __restrict__ H1,
                                                int M, int N) {
    int idx = (blockIdx.x * 256 + threadIdx.x) * 4;
    if (idx < M) {
        float4 v = *(const float4*)(X + idx);
        union { __half2 h[2]; float2 f; } u;
        u.h[0] = __floats2half2_rn(v.x, v.y);
        u.h[1] = __floats2half2_rn(v.z, v.w);
        *(float2*)(XH + idx) = u.f;
    }
    if (blockIdx.x == 0 && threadIdx.x < 16) {
        float4 z = {0.f, 0.f, 0.f, 0.f};
        if (threadIdx.x < 8)
            ((float4*)(XH + (size_t)N * CH))[threadIdx.x] = z;
        else
            ((float4*)(H1 + (size_t)N * CH))[threadIdx.x - 8] = z;
    }
}

// ---- Mean-aggregate: one wave/node, 8 lanes/edge, 4 loads in flight,
//      clamp-to-zero-row prefetch; fp16 output ----
__global__ __launch_bounds__(256) void k_agg(const float4* __restrict__ X4,
                                             const int* __restrict__ offs,
                                             const int* __restrict__ scol,
                                             __half* __restrict__ AGGH, int N, int Em1) {
    int node = blockIdx.x * 4 + (threadIdx.x >> 6);
    int lane = threadIdx.x & 63;
    if (node >= N) return;
    int s = offs[node], e = offs[node + 1];
    int sub = lane & 7;
    int grp = lane >> 3;
    int j = s + grp;
    int i0 = scol[min(j, Em1)];       i0 = (j < e)      ? i0 : N;
    int i1 = scol[min(j + 8, Em1)];   i1 = (j + 8 < e)  ? i1 : N;
    int i2 = scol[min(j + 16, Em1)];  i2 = (j + 16 < e) ? i2 : N;
    int i3 = scol[min(j + 24, Em1)];  i3 = (j + 24 < e) ? i3 : N;
    float4 r0 = X4[(size_t)i0 * 8 + sub];
    float4 r1 = X4[(size_t)i1 * 8 + sub];
    float4 r2 = X4[(size_t)i2 * 8 + sub];
    float4 r3 = X4[(size_t)i3 * 8 + sub];
    float a[8];
#pragma unroll
    for (int k = 0; k < 8; ++k) a[k] = 0.f;
    {
        const __half2* h0 = (const __half2*)&r0;
        const __half2* h1 = (const __half2*)&r1;
        const __half2* h2 = (const __half2*)&r2;
        const __half2* h3 = (const __half2*)&r3;
#pragma unroll
        for (int p = 0; p < 4; ++p) {
            float2 f0 = __half22float2(h0[p]);
            float2 f1 = __half22float2(h1[p]);
            float2 f2 = __half22float2(h2[p]);
            float2 f3 = __half22float2(h3[p]);
            a[2 * p]     += (f0.x + f1.x) + (f2.x + f3.x);
            a[2 * p + 1] += (f0.y + f1.y) + (f2.y + f3.y);
        }
    }
    for (j += 32; j < e; j += 8) {  // rare tail: deg > 32
        float4 r = X4[(size_t)scol[j] * 8 + sub];
        const __half2* h = (const __half2*)&r;
#pragma unroll
        for (int p = 0; p < 4; ++p) {
            float2 f = __half22float2(h[p]);
            a[2 * p]     += f.x;
            a[2 * p + 1] += f.y;
        }
    }
#pragma unroll
    for (int off = 32; off >= 8; off >>= 1)
#pragma unroll
        for (int k = 0; k < 8; ++k)
            a[k] += __shfl_down(a[k], off, 64);
    if (lane < 8) {
        float inv = (e > s) ? 1.0f / (float)(e - s) : 1.0f;
        union { __half2 h[4]; float4 f; } u;
        u.h[0] = __floats2half2_rn(a[0] * inv, a[1] * inv);
        u.h[1] = __floats2half2_rn(a[2] * inv, a[3] * inv);
        u.h[2] = __floats2half2_rn(a[4] * inv, a[5] * inv);
        u.h[3] = __floats2half2_rn(a[6] * inv, a[7] * inv);
        *(float4*)(AGGH + (size_t)node * CH + sub * 8) = u.f;
    }
}

// ---- MFMA fragment helpers -------------------------------------------------
// v_mfma_f32_16x16x16_f16 layout (CDNA3-era, m89-verified C/D family):
//   A: lane l holds A[l&15][4*(l>>4)+r]       (4 contiguous halves along K)
//   B: lane l holds B[4*(l>>4)+r][l&15]       (= W[l&15][4*(l>>4)+r] here)
//   D: lane l holds D[4*(l>>4)+r][l&15]
// Per wave: 32 nodes (2 row-tiles of 16), 64 out channels (4 col-tiles),
// K = 128 (8 K-chunks of 16). W fp32 -> fp16 converted in-register (L1-hot).

// ---- layer-1: h1 = relu(cat(xh,agg).W1^T + b1), fp16 out ----
__global__ __launch_bounds__(256) void k_gemm(const __half* __restrict__ A,
                                              const __half* __restrict__ AGGH,
                                              const float* __restrict__ W,
                                              const float* __restrict__ bias,
                                              __half* __restrict__ OUT, int N) {
    int w = threadIdx.x >> 6;
    int lane = threadIdx.x & 63;
    int lrow = lane & 15;
    int lk = lane >> 4;
    int nb = blockIdx.x * 128 + w * 32;

    // B fragments: bfr[ct][kc] holds W[ct*16+lrow][kc*16+4*lk .. +3] as fp16
    half4_t bfr[4][8];
#pragma unroll
    for (int ct = 0; ct < 4; ++ct) {
        const float* wr = W + (ct * 16 + lrow) * 128 + 4 * lk;
#pragma unroll
        for (int kc = 0; kc < 8; ++kc) {
            float4 v = *(const float4*)(wr + kc * 16);
            half4_t h = {(_Float16)v.x, (_Float16)v.y, (_Float16)v.z, (_Float16)v.w};
            bfr[ct][kc] = h;
        }
    }

#pragma unroll
    for (int t2 = 0; t2 < 2; ++t2) {
        int ar = nb + t2 * 16 + lrow;
        int arx = min(ar, N);      // xh has zeroed dummy row N
        int ara = min(ar, N - 1);  // aggh: clamp to a real row (finite junk, unstored)
        const __half* xrow = A + (size_t)arx * CH + 4 * lk;
        const __half* grow = AGGH + (size_t)ara * CH + 4 * lk;
        half4_t af[8];
#pragma unroll
        for (int kc = 0; kc < 4; ++kc) {
            af[kc]     = *(const half4_t*)(xrow + kc * 16);
            af[kc + 4] = *(const half4_t*)(grow + kc * 16);
        }
        f32x4 acc[4];
#pragma unroll
        for (int ct = 0; ct < 4; ++ct) acc[ct] = (f32x4){0.f, 0.f, 0.f, 0.f};
#pragma unroll
        for (int kc = 0; kc < 8; ++kc)
#pragma unroll
            for (int ct = 0; ct < 4; ++ct)
                acc[ct] = __builtin_amdgcn_mfma_f32_16x16x16f16(af[kc], bfr[ct][kc],
                                                                acc[ct], 0, 0, 0);
#pragma unroll
        for (int ct = 0; ct < 4; ++ct) {
            float bv = bias[ct * 16 + lrow];
#pragma unroll
            for (int r = 0; r < 4; ++r) {
                int gn = nb + t2 * 16 + 4 * lk + r;
                if (gn < N) {
                    float v = fmaxf(acc[ct][r] + bv, 0.f);
                    OUT[(size_t)gn * CH + ct * 16 + lrow] = __float2half(v);
                }
            }
        }
    }
}

// ---- layer-2 + layer-3 dots: t[n]=relu(h2).W3[0:64], s[n]=relu(h2).W3[64:128] ----
__global__ __launch_bounds__(256) void k_gemm2(const __half* __restrict__ A,
                                               const __half* __restrict__ AGGH,
                                               const float* __restrict__ W,
                                               const float* __restrict__ bias,
                                               const float* __restrict__ W3,
                                               float* __restrict__ tarr,
                                               float* __restrict__ sarr, int N) {
    int w = threadIdx.x >> 6;
    int lane = threadIdx.x & 63;
    int lrow = lane & 15;
    int lk = lane >> 4;
    int nb = blockIdx.x * 128 + w * 32;

    half4_t bfr[4][8];
    float bv[4], w3s[4], w3a[4];
#pragma unroll
    for (int ct = 0; ct < 4; ++ct) {
        const float* wr = W + (ct * 16 + lrow) * 128 + 4 * lk;
#pragma unroll
        for (int kc = 0; kc < 8; ++kc) {
            float4 v = *(const float4*)(wr + kc * 16);
            half4_t h = {(_Float16)v.x, (_Float16)v.y, (_Float16)v.z, (_Float16)v.w};
            bfr[ct][kc] = h;
        }
        bv[ct]  = bias[ct * 16 + lrow];
        w3s[ct] = W3[ct * 16 + lrow];
        w3a[ct] = W3[64 + ct * 16 + lrow];
    }

#pragma unroll
    for (int t2 = 0; t2 < 2; ++t2) {
        int ar = nb + t2 * 16 + lrow;
        int arx = min(ar, N);
        int ara = min(ar, N - 1);
        const __half* xrow = A + (size_t)arx * CH + 4 * lk;
        const __half* grow = AGGH + (size_t)ara * CH + 4 * lk;
        half4_t af[8];
#pragma unroll
        for (int kc = 0; kc < 4; ++kc) {
            af[kc]     = *(const half4_t*)(xrow + kc * 16);
            af[kc + 4] = *(const half4_t*)(grow + kc * 16);
        }
        f32x4 acc[4];
#pragma unroll
        for (int ct = 0; ct < 4; ++ct) acc[ct] = (f32x4){0.f, 0.f, 0.f, 0.f};
#pragma unroll
        for (int kc = 0; kc < 8; ++kc)
#pragma unroll
            for (int ct = 0; ct < 4; ++ct)
                acc[ct] = __builtin_amdgcn_mfma_f32_16x16x16f16(af[kc], bfr[ct][kc],
                                                                acc[ct], 0, 0, 0);
#pragma unroll
        for (int r = 0; r < 4; ++r) {
            float tp = 0.f, sp = 0.f;
#pragma unroll
            for (int ct = 0; ct < 4; ++ct) {
                float v = fmaxf(acc[ct][r] + bv[ct], 0.f);
                tp += v * w3s[ct];
                sp += v * w3a[ct];
            }
#pragma unroll
            for (int off = 1; off <= 8; off <<= 1) {
                tp += __shfl_xor(tp, off, 16);
                sp += __shfl_xor(sp, off, 16);
            }
            int gn = nb + t2 * 16 + 4 * lk + r;
            if (lrow == 0 && gn < N) {
                tarr[gn] = tp;
                sarr[gn] = sp;
            }
        }
    }
}

// ---- Final: out[n] = t[n] + mean_j s[col_j] + b3 (4B/edge gather) ----
__global__ __launch_bounds__(256) void k_fin(const float* __restrict__ tarr,
                                             const float* __restrict__ sarr,
                                             const int* __restrict__ offs,
                                             const int* __restrict__ scol,
                                             const float* __restrict__ b3,
                                             float* __restrict__ out, int N) {
    int n = blockIdx.x * 256 + threadIdx.x;
    if (n >= N) return;
    int s = offs[n], e = offs[n + 1];
    float s0 = 0.f, s1 = 0.f, s2 = 0.f, s3 = 0.f;
    int j = s;
    for (; j + 4 <= e; j += 4) {
        s0 += sarr[scol[j]];
        s1 += sarr[scol[j + 1]];
        s2 += sarr[scol[j + 2]];
        s3 += sarr[scol[j + 3]];
    }
    for (; j < e; ++j) s0 += sarr[scol[j]];
    float inv = (e > s) ? 1.0f / (float)(e - s) : 1.0f;
    out[n] = tarr[n] + ((s0 + s1) + (s2 + s3)) * inv + b3[0];
}

extern "C" void kernel_launch(void* const* d_in, const int* in_sizes, int n_in,
                              void* d_out, int out_size, void* d_ws, size_t ws_size,
                              hipStream_t stream) {
    const float* x   = (const float*)d_in[0];
    const int* eidx  = (const int*)d_in[1];
    const float* W1  = (const float*)d_in[2];
    const float* b1  = (const float*)d_in[3];
    const float* W2  = (const float*)d_in[4];
    const float* b2  = (const float*)d_in[5];
    const float* W3  = (const float*)d_in[6];
    const float* b3  = (const float*)d_in[7];
    float* out = (float*)d_out;

    const int N = in_sizes[0] / CH;
    const int E = in_sizes[1] / 2;
    const int* row = eidx;
    const int* col = eidx + E;

    int offs_sz = ((N + 1 + 3) / 4) * 4;
    int e_sz    = ((E + 3) / 4) * 4;
    size_t tbl  = (size_t)(N + 1) * CH;  // halves per table (incl. zero row)

    int* offs    = (int*)d_ws;                      // offs_sz ints
    int* scol    = offs + offs_sz;                  // e_sz ints
    __half* xh   = (__half*)(scol + e_sz);          // tbl halves
    __half* h1   = xh + tbl;                        // tbl halves
    __half* aggh = h1 + tbl;                        // N*CH halves
    float* tarr  = (float*)(aggh + (size_t)N * CH); // N floats
    float* sarr  = tarr + N;                        // N floats
    // sort scratch aliases aggh region (dead before aggh's first write)
    int* ebuf   = (int*)aggh;                       // E ints
    int nbk     = (N + BKT_ROWS - 1) >> BKT_SHIFT;
    int* hist   = ebuf + e_sz;                      // nbk*NBLK
    int* histsc = hist + (size_t)nbk * NBLK;        // nbk*NBLK
    int* part   = histsc + (size_t)nbk * NBLK;      // scan partials

    int M = nbk * NBLK;
    int per_blk = (E + NBLK - 1) / NBLK;
    int mb = (M + 1023) / 1024;
    int abl = (N + 3) / 4;
    int gbl = (N + 127) / 128;
    int cvb = (N * CH / 4 + 255) / 256;

    // CSR build
    k_hist<<<NBLK, 256, 0, stream>>>(row, hist, E, nbk, per_blk);
    k_ssum<<<mb, 256, 0, stream>>>(hist, part, M);
    k_sser<<<1, 64, 0, stream>>>(part, mb);
    k_sscan<<<mb, 256, 0, stream>>>(hist, part, histsc, M);
    k_binscatter<<<NBLK, 256, 0, stream>>>(row, col, histsc, ebuf, E, nbk, per_blk);
    k_build<<<nbk, 256, 0, stream>>>(histsc, ebuf, offs, scol, N, E, nbk);

    // x -> fp16 table (+ zero dummy rows of xh, h1)
    k_tohalf<<<cvb, 256, 0, stream>>>(x, xh, h1, N * CH, N);

    // layer 1
    k_agg<<<abl, 256, 0, stream>>>((const float4*)xh, offs, scol, aggh, N, E - 1);
    k_gemm<<<gbl, 256, 0, stream>>>(xh, aggh, W1, b1, h1, N);
    // layer 2 (+ fused layer-3 dots)
    k_agg<<<abl, 256, 0, stream>>>((const float4*)h1, offs, scol, aggh, N, E - 1);
    k_gemm2<<<gbl, 256, 0, stream>>>(h1, aggh, W2, b2, W3, tarr, sarr, N);
    // layer 3 finish
    k_fin<<<(N + 255) / 256, 256, 0, stream>>>(tarr, sarr, offs, scol, b3, out, N);
}